// Round 15
// baseline (389.741 us; speedup 1.0000x reference)
//
#include <hip/hip_runtime.h>
#include <math.h>

// Problem constants
#define NB     64
#define N1V    8192
#define NV     778
#define NVP    780
#define NFACE  1538
#define NZ     64
#define NPAR   61
#define NPRIOR 204
#define GH     0.0125f
#define GINV   80.0f
#define PGH    0.025f
#define PGINV  40.0f
#define SLACK  1e-6f

// roles
#define REC_BLOCKS 4096               // (batch, 64 blocks) x 4 waves = 256 wave slots
#define GT_BLOCKS  4096
#define CH_BLOCKS  128
#define NROLE (REC_BLOCKS + GT_BLOCKS + CH_BLOCKS)
#define CMB_BLOCKS 64

// ws per-batch float4 layout (stride BATCH_F4):
//   [0,780) recS sorted (x,y,z,|t|^2) | [780,1560) nrmS sorted | [1560,2340) gtS
//   [2340,2544) priS sorted by 4^3 cell
//   at f4 2544 (u16): rcs[513], +520: gcs[513], +1040: pcs[65]
#define BATCH_F4 2688
#define ACC_OFF  (NB * BATCH_F4 * 4)
#define ENT_OFF  (ACC_OFF + 16)          // u32[NB*256] wave entries
#define PERM_OFF (ENT_OFF + 16384)       // u16[NB*16384] sorted point indices
#define RC_OFF   (PERM_OFF + 524288)     // ull[NB*256] rec-cmap bits
#define GC_OFF   (RC_OFF + 32768)        // ull[NB*256] gt-cmap bits
// acc slots: 2 chamfer, 3 S_cmap, 4 N_cmap, 5 N_gt, 6 N_cons, 7 S_pen, 15 ticket

__device__ __constant__ int c_prior[NPRIOR] = {
  697,698,699,700,712,713,714,715,737,738,739,740,741,743,744,745,746,748,749,750,
  753,754,755,756,757,758,759,760,761,762,763,764,765,766,767,768,
  46,47,48,49,164,165,166,167,194,195,223,237,238,280,281,298,301,317,320,323,
  324,325,326,327,328,329,330,331,332,333,340,341,342,343,344,345,346,347,348,349,
  350,351,352,353,354,355,
  356,357,358,359,375,376,386,387,396,397,402,403,413,429,433,434,435,436,437,438,
  439,440,441,442,443,444,452,453,454,455,456,459,460,461,462,463,464,465,466,467,
  468,469,470,471,484,485,486,496,497,506,507,513,514,524,545,546,547,548,549,550,
  551,552,553,555,563,564,565,566,567,570,572,573,574,575,576,577,578,
  580,581,582,583,600,601,602,614,615,624,625,630,631,641,663,664,665,666,667,668,
  670,672,680,681,682,683,684,686,687,688,689,690,691,692,693,694,695,
  73,96,98,99,772,774,775,777
};

__device__ __forceinline__ int cell8(float x, float y, float z) {
    int cx = min(7, max(0, (int)(x * GINV)));
    int cy = min(7, max(0, (int)(y * GINV)));
    int cz = min(7, max(0, (int)(z * GINV)));
    return (cz * 8 + cy) * 8 + cx;
}

// ---------------- Kernel 0: [0,NB) target prep  [NB,2NB) obj binning --------
__global__ __launch_bounds__(256) void k_prep(const float* __restrict__ recon,
                                              const float* __restrict__ gt,
                                              const float* __restrict__ obj,
                                              const int* __restrict__ faces,
                                              float4* __restrict__ ws4,
                                              float* __restrict__ acc,
                                              unsigned int* __restrict__ ent,
                                              unsigned short* __restrict__ perm) {
    int tid = threadIdx.x;
    if (blockIdx.x >= NB) {
        // ============ OBJ BINNING (128 groups of 2x2x1 cells) ============
        int b = blockIdx.x - NB;
        __shared__ unsigned int bcnt[128], bcnt2[128];
        __shared__ unsigned short bstart[128];
        __shared__ unsigned int s_entt[256];
        if (tid < 128) { bcnt[tid] = 0u; bcnt2[tid] = 0u; }
        s_entt[tid] = 0u;
        __syncthreads();
        const float* ob = obj + (size_t)b * N1V * 3;
        for (int i = tid; i < N1V; i += 256) {
            float x = ob[3*i], y = ob[3*i+1], z = ob[3*i+2];
            int cx = min(7, max(0, (int)(x * GINV)));
            int cy = min(7, max(0, (int)(y * GINV)));
            int cz = min(7, max(0, (int)(z * GINV)));
            int g = (((cz << 2) + (cy >> 1)) << 2) | (cx >> 1);
            atomicAdd(&bcnt[g], 1u);
        }
        __syncthreads();
        if (tid == 0) {
            unsigned int slot = 0;
            for (int g = 0; g < 128; ++g) {
                bstart[g] = (unsigned short)slot;
                slot += ((bcnt[g] + 63u) >> 6) << 6;
            }
        }
        __syncthreads();
        for (int g = tid; g < 128; g += 256) {
            unsigned int c = bcnt[g];
            int nw = (int)((c + 63u) >> 6);
            int wb = ((int)bstart[g]) >> 6;
            for (int i = 0; i < nw; ++i) {
                unsigned int nv = min(64u, c - 64u * (unsigned)i);
                s_entt[wb + i] = (unsigned)g | (nv << 8);
            }
        }
        __syncthreads();
        ent[b * 256 + tid] = s_entt[tid];
        for (int i = tid; i < N1V; i += 256) {
            float x = ob[3*i], y = ob[3*i+1], z = ob[3*i+2];
            int cx = min(7, max(0, (int)(x * GINV)));
            int cy = min(7, max(0, (int)(y * GINV)));
            int cz = min(7, max(0, (int)(z * GINV)));
            int g = (((cz << 2) + (cy >> 1)) << 2) | (cx >> 1);
            unsigned int r = atomicAdd(&bcnt2[g], 1u);
            perm[(size_t)b * 16384 + bstart[g] + r] = (unsigned short)i;
        }
        return;
    }
    // ============ TARGET PREP (r14-verified + sorted prior) ============
    int b = blockIdx.x;
    if (b == 0 && tid < 16) acc[tid] = 0.0f;
    __shared__ float4 s_r[NV];
    __shared__ float s_vnx[NV], s_vny[NV], s_vnz[NV];
    __shared__ unsigned int s_cnt[512];
    __shared__ unsigned short s_start[513];
    __shared__ unsigned int pcnt[64];
    __shared__ unsigned short pst[65];

    float4* base4 = ws4 + (size_t)b * BATCH_F4;
    float4* recS = base4;
    float4* nrmS = base4 + NVP;
    float4* gtS  = base4 + 2 * NVP;
    float4* priS = base4 + 3 * NVP;
    unsigned short* rcs = (unsigned short*)(ws4 + (size_t)b * BATCH_F4 + 2544);
    unsigned short* gcs = rcs + 520;
    unsigned short* pcs = rcs + 1040;

    const float* rb = recon + (size_t)b * NV * 3;
    const float* gb = gt    + (size_t)b * NV * 3;

    // ---------- phase A: rec ----------
    for (int j = tid; j < NV; j += 256) {
        float x = rb[3*j], y = rb[3*j+1], z = rb[3*j+2];
        s_r[j] = make_float4(x, y, z, x*x + y*y + z*z);
        s_vnx[j] = 0.0f; s_vny[j] = 0.0f; s_vnz[j] = 0.0f;
    }
    s_cnt[tid] = 0u; s_cnt[tid + 256] = 0u;
    __syncthreads();
    for (int f = tid; f < NFACE; f += 256) {
        int i0 = faces[3*f], i1 = faces[3*f+1], i2 = faces[3*f+2];
        float4 p0 = s_r[i0], p1 = s_r[i1], p2 = s_r[i2];
        float e1x = p1.x - p0.x, e1y = p1.y - p0.y, e1z = p1.z - p0.z;
        float e2x = p2.x - p0.x, e2y = p2.y - p0.y, e2z = p2.z - p0.z;
        float fx = e1y * e2z - e1z * e2y;
        float fy = e1z * e2x - e1x * e2z;
        float fz = e1x * e2y - e1y * e2x;
        atomicAdd(&s_vnx[i0], fx); atomicAdd(&s_vny[i0], fy); atomicAdd(&s_vnz[i0], fz);
        atomicAdd(&s_vnx[i1], fx); atomicAdd(&s_vny[i1], fy); atomicAdd(&s_vnz[i1], fz);
        atomicAdd(&s_vnx[i2], fx); atomicAdd(&s_vny[i2], fy); atomicAdd(&s_vnz[i2], fz);
    }
    __syncthreads();
    for (int j = tid; j < NV; j += 256) {
        float x = s_vnx[j], y = s_vny[j], z = s_vnz[j];
        float inv = 1.0f / (sqrtf(x*x + y*y + z*z) + 1e-12f);
        s_vnx[j] = x * inv; s_vny[j] = y * inv; s_vnz[j] = z * inv;
    }
    for (int j = tid; j < NV; j += 256) {
        float4 v = s_r[j];
        atomicAdd(&s_cnt[cell8(v.x, v.y, v.z)], 1u);
    }
    __syncthreads();
    for (int off = 1; off < 512; off <<= 1) {
        unsigned int a0 = (tid >= off) ? s_cnt[tid - off] : 0u;
        int i2 = tid + 256;
        unsigned int a1 = (i2 >= off) ? s_cnt[i2 - off] : 0u;
        __syncthreads();
        s_cnt[tid] += a0; s_cnt[i2] += a1;
        __syncthreads();
    }
    if (tid == 0) s_start[0] = 0;
    s_start[tid + 1]   = (unsigned short)s_cnt[tid];
    s_start[tid + 257] = (unsigned short)s_cnt[tid + 256];
    __syncthreads();
    rcs[tid] = s_start[tid]; rcs[tid + 256] = s_start[tid + 256];
    if (tid == 0) rcs[512] = s_start[512];
    s_cnt[tid] = 0u; s_cnt[tid + 256] = 0u;
    __syncthreads();
    for (int j = tid; j < NV; j += 256) {
        float4 v = s_r[j];
        int c = cell8(v.x, v.y, v.z);
        int pos = (int)s_start[c] + (int)atomicAdd(&s_cnt[c], 1u);
        recS[pos] = v;
        nrmS[pos] = make_float4(s_vnx[j], s_vny[j], s_vnz[j], 0.0f);
    }
    // ---------- prior: sorted by 4^3 cell ----------
    if (tid < 64) pcnt[tid] = 0u;
    __syncthreads();
    for (int k = tid; k < NPRIOR; k += 256) {
        float4 v = s_r[c_prior[k]];
        int cx = min(3, max(0, (int)(v.x * PGINV)));
        int cy = min(3, max(0, (int)(v.y * PGINV)));
        int cz = min(3, max(0, (int)(v.z * PGINV)));
        atomicAdd(&pcnt[(((cz << 2) + cy) << 2) | cx], 1u);
    }
    __syncthreads();
    if (tid == 0) {
        unsigned int r = 0;
        for (int c = 0; c < 64; ++c) { pst[c] = (unsigned short)r; r += pcnt[c]; }
        pst[64] = (unsigned short)r;
    }
    __syncthreads();
    if (tid < 65) pcs[tid] = pst[tid];
    if (tid < 64) pcnt[tid] = 0u;
    __syncthreads();
    for (int k = tid; k < NPRIOR; k += 256) {
        float4 v = s_r[c_prior[k]];
        int cx = min(3, max(0, (int)(v.x * PGINV)));
        int cy = min(3, max(0, (int)(v.y * PGINV)));
        int cz = min(3, max(0, (int)(v.z * PGINV)));
        int c = (((cz << 2) + cy) << 2) | cx;
        int pos = (int)pst[c] + (int)atomicAdd(&pcnt[c], 1u);
        priS[pos] = v;
    }
    __syncthreads();
    // ---------- phase B: gt ----------
    for (int j = tid; j < NV; j += 256) {
        float x = gb[3*j], y = gb[3*j+1], z = gb[3*j+2];
        s_r[j] = make_float4(x, y, z, x*x + y*y + z*z);
    }
    s_cnt[tid] = 0u; s_cnt[tid + 256] = 0u;
    __syncthreads();
    for (int j = tid; j < NV; j += 256) {
        float4 v = s_r[j];
        atomicAdd(&s_cnt[cell8(v.x, v.y, v.z)], 1u);
    }
    __syncthreads();
    for (int off = 1; off < 512; off <<= 1) {
        unsigned int a0 = (tid >= off) ? s_cnt[tid - off] : 0u;
        int i2 = tid + 256;
        unsigned int a1 = (i2 >= off) ? s_cnt[i2 - off] : 0u;
        __syncthreads();
        s_cnt[tid] += a0; s_cnt[i2] += a1;
        __syncthreads();
    }
    if (tid == 0) s_start[0] = 0;
    s_start[tid + 1]   = (unsigned short)s_cnt[tid];
    s_start[tid + 257] = (unsigned short)s_cnt[tid + 256];
    __syncthreads();
    gcs[tid] = s_start[tid]; gcs[tid + 256] = s_start[tid + 256];
    if (tid == 0) gcs[512] = s_start[512];
    s_cnt[tid] = 0u; s_cnt[tid + 256] = 0u;
    __syncthreads();
    for (int j = tid; j < NV; j += 256) {
        float4 v = s_r[j];
        int c = cell8(v.x, v.y, v.z);
        int pos = (int)s_start[c] + (int)atomicAdd(&s_cnt[c], 1u);
        gtS[pos] = v;
    }
}

// ---------------- Fused role kernel ----------------
// [0,4096): rec  [4096,8192): gt  [8192,8320): chamfer
__global__ __launch_bounds__(256) void k_fused(const float* __restrict__ obj,
                                               const float4* __restrict__ ws4,
                                               float* __restrict__ acc,
                                               const unsigned int* __restrict__ ent,
                                               const unsigned short* __restrict__ perm,
                                               unsigned long long* __restrict__ rcU,
                                               unsigned long long* __restrict__ gcU) {
    __shared__ float4 s_t[NVP];
    __shared__ float4 s_pri[NPRIOR];
    __shared__ unsigned short s_cs[520];
    __shared__ unsigned short s_pcs[72];
    __shared__ unsigned int s_ent[4];
    __shared__ float s_red[3];
    int tid = threadIdx.x, blk = blockIdx.x;
    int lane = tid & 63, wv = tid >> 6;

    if (blk < REC_BLOCKS + GT_BLOCKS) {
        bool isrec = blk < REC_BLOCKS;
        int r = isrec ? blk : (blk - REC_BLOCKS);
        int b = r >> 6, wbase = (r & 63) << 2;
        const float4* base4 = ws4 + (size_t)b * BATCH_F4;
        const unsigned short* rcs = (const unsigned short*)(ws4 + (size_t)b * BATCH_F4 + 2544);
        const float4* tgt = isrec ? base4 : (base4 + 2 * NVP);
        int csoff = isrec ? 0 : 520;
        for (int j = tid; j < NV; j += 256) s_t[j] = tgt[j];
        for (int t = tid; t < 513; t += 256) s_cs[t] = rcs[csoff + t];
        if (isrec) {
            for (int k = tid; k < NPRIOR; k += 256) s_pri[k] = base4[3 * NVP + k];
            if (tid < 65) s_pcs[tid] = rcs[1040 + tid];
        }
        if (tid < 4) s_ent[tid] = ent[b * 256 + wbase + tid];
        if (tid < 3) s_red[tid] = 0.0f;
        __syncthreads();

        unsigned int e = s_ent[wv];
        int nval = (int)(e >> 8);
        int slot = b * 256 + wbase + wv;
        float lS_cmap = 0.0f, lN_cmap = 0.0f, lS_pen = 0.0f, lN_gt = 0.0f;
        unsigned long long bits = 0ull;
        if (nval > 0) {
            int g = (int)(e & 0xFFu);
            int gx = g & 3, gy = (g >> 2) & 3, cz = g >> 4;
            bool valid = lane < nval;
            float px = 0.05f, py = 0.05f, pz = 0.05f;
            if (valid) {
                int idx = (int)perm[(size_t)b * 16384 + (size_t)((wbase + wv) << 6) + lane];
                const float* p = obj + ((size_t)b * N1V + idx) * 3;
                px = p[0]; py = p[1]; pz = p[2];
            }
            float nax = -2.0f * px, nay = -2.0f * py, naz = -2.0f * pz;
            float a2 = px*px + py*py + pz*pz;
            // wave-uniform candidate scan over group neighborhood (<=48 cells)
            int x0 = max(0, 2*gx - 1), x1 = min(7, 2*gx + 2);
            int y0 = max(0, 2*gy - 1), y1 = min(7, 2*gy + 2);
            int z0 = max(0, cz - 1),   z1 = min(7, cz + 1);
            float best = 3.4e38f; int bi = 0;
#pragma unroll 1
            for (int z = z0; z <= z1; ++z)
#pragma unroll 1
            for (int y = y0; y <= y1; ++y) {
                int rb_ = (z * 8 + y) * 8;
                int s = s_cs[rb_ + x0], en = s_cs[rb_ + x1 + 1];
#pragma unroll 1
                for (int t = s; t < en; ++t) {
                    float4 q = s_t[t];
                    float d = fmaf(nax, q.x, fmaf(nay, q.y, fmaf(naz, q.z, q.w)));
                    if (d < best) { best = d; bi = t; }
                }
            }
            // per-point proof vs group box (domain faces excluded)
            float bxm = (x0 > 0) ? (px - (float)x0 * GH) : 1e30f;
            float bxp = (x1 < 7) ? ((float)(x1 + 1) * GH - px) : 1e30f;
            float bym = (y0 > 0) ? (py - (float)y0 * GH) : 1e30f;
            float byp = (y1 < 7) ? ((float)(y1 + 1) * GH - py) : 1e30f;
            float bzm = (z0 > 0) ? (pz - (float)z0 * GH) : 1e30f;
            float bzp = (z1 < 7) ? ((float)(z1 + 1) * GH - pz) : 1e30f;
            float bm = fminf(fminf(fminf(bxm, bxp), fminf(bym, byp)), fminf(bzm, bzp));
            bool unproven = valid && !(a2 + best + SLACK < bm * bm);
            if (__any(unproven)) {
                if (unproven) {
                    best = 3.4e38f; bi = 0;
#pragma unroll 1
                    for (int t = 0; t < NV; ++t) {
                        float4 q = s_t[t];
                        float d = fmaf(nax, q.x, fmaf(nay, q.y, fmaf(naz, q.z, q.w)));
                        if (d < best) { best = d; bi = t; }
                    }
                }
            }
            if (isrec) {
                // prior scan over 4^3 supercell neighborhood (wave-uniform)
                int sx = gx, sy = gy, sz = cz >> 1;
                int qx0 = max(0, sx - 1), qx1 = min(3, sx + 1);
                int qy0 = max(0, sy - 1), qy1 = min(3, sy + 1);
                int qz0 = max(0, sz - 1), qz1 = min(3, sz + 1);
                float mp = 3.4e38f;
#pragma unroll 1
                for (int z = qz0; z <= qz1; ++z)
#pragma unroll 1
                for (int y = qy0; y <= qy1; ++y) {
                    int rb_ = (z * 4 + y) * 4;
                    int s = s_pcs[rb_ + qx0], en = s_pcs[rb_ + qx1 + 1];
#pragma unroll 1
                    for (int t = s; t < en; ++t) {
                        float4 q = s_pri[t];
                        float d = fmaf(nax, q.x, fmaf(nay, q.y, fmaf(naz, q.z, q.w)));
                        mp = fminf(mp, d);
                    }
                }
                float cxm = (qx0 > 0) ? (px - (float)qx0 * PGH) : 1e30f;
                float cxp = (qx1 < 3) ? ((float)(qx1 + 1) * PGH - px) : 1e30f;
                float cym = (qy0 > 0) ? (py - (float)qy0 * PGH) : 1e30f;
                float cyp = (qy1 < 3) ? ((float)(qy1 + 1) * PGH - py) : 1e30f;
                float czm = (qz0 > 0) ? (pz - (float)qz0 * PGH) : 1e30f;
                float czp = (qz1 < 3) ? ((float)(qz1 + 1) * PGH - pz) : 1e30f;
                float pbm = fminf(fminf(fminf(cxm, cxp), fminf(cym, cyp)), fminf(czm, czp));
                bool unp2 = valid && !(a2 + mp + SLACK < pbm * pbm);
                if (__any(unp2)) {
                    if (unp2) {
                        mp = 3.4e38f;
#pragma unroll 1
                        for (int t = 0; t < NPRIOR; ++t) {
                            float4 q = s_pri[t];
                            float d = fmaf(nax, q.x, fmaf(nay, q.y, fmaf(naz, q.z, q.w)));
                            mp = fminf(mp, d);
                        }
                    }
                }
                float drec = fmaxf(a2 + best, 0.0f);
                float dpri = fmaxf(a2 + mp, 0.0f);
                if (valid && drec < 1e-4f) { lS_cmap += dpri; lN_cmap += 1.0f; }
                bits = __ballot(valid && (sqrtf(drec) < 0.005f));
                float4 tS = s_t[bi];
                float4 nr = base4[NVP + bi];   // sorted normal, from L2
                float ddot = (tS.x - px) * nr.x + (tS.y - py) * nr.y + (tS.z - pz) * nr.z;
                if (valid && ddot > 0.0f) lS_pen += drec;
            } else {
                float dgt = fmaxf(a2 + best, 0.0f);
                bool gc = valid && (sqrtf(dgt) < 0.005f);
                if (gc) lN_gt += 1.0f;
                bits = __ballot(gc);
            }
        }
        if (lane == 0) { if (isrec) rcU[slot] = bits; else gcU[slot] = bits; }
        if (isrec) {
            atomicAdd(&s_red[0], lS_cmap);
            atomicAdd(&s_red[1], lN_cmap);
            atomicAdd(&s_red[2], lS_pen);
            __syncthreads();
            if (tid == 0) atomicAdd(&acc[3], s_red[0]);
            if (tid == 1) atomicAdd(&acc[4], s_red[1]);
            if (tid == 2) atomicAdd(&acc[7], s_red[2]);
        } else {
            atomicAdd(&s_red[0], lN_gt);
            __syncthreads();
            if (tid == 0) atomicAdd(&acc[5], s_red[0]);
        }
        return;
    }

    // ============ CHAMFER ROLE (r14-verified brute) ============
    {
        int c   = blk - (REC_BLOCKS + GT_BLOCKS);
        int b   = c >> 1;
        int dir = c & 1;           // 0: rec->gt, 1: gt->rec
        const float4* base4 = ws4 + (size_t)b * BATCH_F4;
        const float4* srcv = dir ? (base4 + 2 * NVP) : base4;   // gtS : recS
        const float4* tgtv = dir ? base4 : (base4 + 2 * NVP);   // recS : gtS
        for (int j = tid; j < NV; j += 256) s_t[j] = tgtv[j];
        if (tid < 2) s_t[NV + tid] = make_float4(0.f, 0.f, 0.f, 1e30f);
        if (tid == 0) s_red[0] = 0.0f;
        __syncthreads();

        const int CPT = 4;
        float nax[CPT], nay[CPT], naz[CPT], a2s[CPT], m[CPT];
        bool valid[CPT];
#pragma unroll
        for (int k = 0; k < CPT; ++k) {
            int p = tid + 256 * k;
            valid[k] = (p < NV);
            float4 s = srcv[valid[k] ? p : 0];
            nax[k] = -2.0f * s.x; nay[k] = -2.0f * s.y; naz[k] = -2.0f * s.z;
            a2s[k] = s.x*s.x + s.y*s.y + s.z*s.z;
            m[k] = 3.4e38f;
        }
#pragma unroll 1
        for (int j = 0; j < NVP; j += 4) {
            float4 t0 = s_t[j], t1 = s_t[j+1], t2 = s_t[j+2], t3 = s_t[j+3];
#pragma unroll
            for (int k = 0; k < CPT; ++k) {
                float d0 = fmaf(nax[k], t0.x, fmaf(nay[k], t0.y, fmaf(naz[k], t0.z, t0.w)));
                float d1 = fmaf(nax[k], t1.x, fmaf(nay[k], t1.y, fmaf(naz[k], t1.z, t1.w)));
                float d2 = fmaf(nax[k], t2.x, fmaf(nay[k], t2.y, fmaf(naz[k], t2.z, t2.w)));
                float d3 = fmaf(nax[k], t3.x, fmaf(nay[k], t3.y, fmaf(naz[k], t3.z, t3.w)));
                m[k] = fminf(fminf(m[k], fminf(d0, d1)), fminf(d2, d3));
            }
        }
        float local = 0.0f;
#pragma unroll
        for (int k = 0; k < CPT; ++k)
            if (valid[k]) local += fmaxf(a2s[k] + m[k], 0.0f);
        atomicAdd(&s_red[0], local);
        __syncthreads();
        if (tid == 0) atomicAdd(&acc[2], s_red[0]);
    }
}

// ---------------- Combine (popc rc&gc) + finalize (ticket) ----------------
__global__ __launch_bounds__(256) void k_combine(float* __restrict__ acc,
                                                 const unsigned int* __restrict__ rcW,
                                                 const unsigned int* __restrict__ gcW,
                                                 const float* __restrict__ mean,
                                                 const float* __restrict__ log_var,
                                                 const float* __restrict__ rp,
                                                 const float* __restrict__ xp,
                                                 float* __restrict__ out) {
    int blk = blockIdx.x, tid = threadIdx.x;
    __shared__ float s_red[2];
    __shared__ unsigned int s_ticket;
    if (tid < 2) s_red[tid] = 0.0f;
    __syncthreads();
    float cnt = 0.0f;
    for (int i = blk * 256 + tid; i < 32768; i += CMB_BLOCKS * 256)
        cnt += (float)__popc(rcW[i] & gcW[i]);
    atomicAdd(&s_red[0], cnt);
    __syncthreads();
    if (tid == 0) atomicAdd(&acc[6], s_red[0]);
    __threadfence();
    if (tid == 0) s_ticket = atomicAdd((unsigned int*)&acc[15], 1u);
    __syncthreads();

    if (s_ticket == CMB_BLOCKS - 1) {
        if (tid < 2) s_red[tid] = 0.0f;
        __syncthreads();
        float s_param = 0.0f, s_kld = 0.0f;
        for (int i = tid; i < NB * NPAR; i += 256) {
            float d = rp[i] - xp[i];
            s_param += d * d;
        }
        for (int i = tid; i < NB * NZ; i += 256) {
            float m = mean[i], lv = log_var[i];
            s_kld += 1.0f + lv - m * m - expf(lv);
        }
        atomicAdd(&s_red[0], s_param);
        atomicAdd(&s_red[1], s_kld);
        __syncthreads();
        if (tid == 0) {
            const float fB = 64.0f;
            float a2v = atomicAdd(&acc[2], 0.0f);
            float a3  = atomicAdd(&acc[3], 0.0f);
            float a4  = atomicAdd(&acc[4], 0.0f);
            float a5  = atomicAdd(&acc[5], 0.0f);
            float a6  = atomicAdd(&acc[6], 0.0f);
            float a7  = atomicAdd(&acc[7], 0.0f);
            float param_loss  = s_red[0] / fB;
            float KLD         = -0.5f * s_red[1] / fB * 10.0f;
            float recon_loss  = a2v / fB;
            float cmap_loss   = 3000.0f * a3 / (fB * a4);
            float consistency = -5.0f * a6 / (a5 + 0.0001f);
            float penetr      = 100.0f * a7 / fB;
            out[0] = (recon_loss + KLD) + 0.1f * param_loss + 1000.0f * cmap_loss
                   + 10.0f * consistency + 10.0f * penetr;
        }
    }
}

extern "C" void kernel_launch(void* const* d_in, const int* in_sizes, int n_in,
                              void* d_out, int out_size, void* d_ws, size_t ws_size,
                              hipStream_t stream) {
    (void)in_sizes; (void)n_in; (void)out_size; (void)ws_size;
    const float* obj     = (const float*)d_in[0];
    const float* recon   = (const float*)d_in[1];
    const float* gt      = (const float*)d_in[2];
    const float* mean    = (const float*)d_in[3];
    const float* log_var = (const float*)d_in[4];
    const float* rp      = (const float*)d_in[5];
    const float* xp      = (const float*)d_in[6];
    const int*   faces   = (const int*)d_in[7];
    float4* ws4 = (float4*)d_ws;
    float* acc  = (float*)d_ws + ACC_OFF;
    unsigned int* ent   = (unsigned int*)((float*)d_ws + ENT_OFF);
    unsigned short* perm = (unsigned short*)((float*)d_ws + PERM_OFF);
    unsigned long long* rcU = (unsigned long long*)((float*)d_ws + RC_OFF);
    unsigned long long* gcU = (unsigned long long*)((float*)d_ws + GC_OFF);
    float* out  = (float*)d_out;

    k_prep   <<<2 * NB,     256, 0, stream>>>(recon, gt, obj, faces, ws4, acc, ent, perm);
    k_fused  <<<NROLE,      256, 0, stream>>>(obj, ws4, acc, ent, perm, rcU, gcU);
    k_combine<<<CMB_BLOCKS, 256, 0, stream>>>(acc, (const unsigned int*)rcU,
                                              (const unsigned int*)gcU,
                                              mean, log_var, rp, xp, out);
}

// Round 16
// 197.190 us; speedup vs baseline: 1.9765x; 1.9765x over previous
//
#include <hip/hip_runtime.h>
#include <math.h>

// Problem constants (from reference setup_inputs)
#define NB     64      // batch
#define N1V    8192    // obj points per batch
#define NPTS   (NB * N1V)
#define NV     778     // recon / gt verts
#define NVP    780     // padded to multiple of 4
#define NQ     195     // target quads
#define SEG1Q  51      // first 51 quads = 204 permuted targets = PRIOR set
#define NFACE  1538
#define NZ     64
#define NPAR   61
#define NPRIOR 204
#define PPT    8       // obj points per thread (rec/gt roles)
#define BIAS   0.0625f // 2|a||t| <= 0.06 < BIAS -> biased rec partials stay >= 0

// k_fused roles
#define REC_BLOCKS 256                 // (batch, chunk-of-2048)
#define GT_BLOCKS  256
#define CH_BLOCKS  128                 // (batch, dir)
#define NROLE_BLOCKS (REC_BLOCKS + GT_BLOCKS + CH_BLOCKS)   // 640
#define CMB_BLOCKS 64                  // 64*256 uints over rc/gc words

// ws float4 layout per batch (BATCH_F4 float4s):
//   [0,780)     gt4    (x,y,z,|t|^2)  original order, pads w=1e30
//   [780,1560)  rec4p  (x,y,z,|t|^2+BIAS) PERMUTED (prior first), pads w=1e30
//   [1560,2340) nrm4p  (nx,ny,nz,0)   PERMUTED to match rec4p
#define BATCH_F4 2352                  // padded stride
// float offsets in ws
#define ACC_OFF (NB * BATCH_F4 * 4)   // acc[16]: [2..7] sums, [15] ticket
#define RC_OFF  (ACC_OFF + 16)        // uchar[NPTS/8] rec-cmap bits (1/pt)
#define GC_OFF  (RC_OFF + NPTS / 32)  // uchar[NPTS/8] gt-cmap bits
// acc slots: 2 chamfer, 3 S_cmap, 4 N_cmap, 5 N_gt, 6 N_cons, 7 S_pen

__device__ __constant__ int c_prior[NPRIOR] = {
  697,698,699,700,712,713,714,715,737,738,739,740,741,743,744,745,746,748,749,750,
  753,754,755,756,757,758,759,760,761,762,763,764,765,766,767,768,
  46,47,48,49,164,165,166,167,194,195,223,237,238,280,281,298,301,317,320,323,
  324,325,326,327,328,329,330,331,332,333,340,341,342,343,344,345,346,347,348,349,
  350,351,352,353,354,355,
  356,357,358,359,375,376,386,387,396,397,402,403,413,429,433,434,435,436,437,438,
  439,440,441,442,443,444,452,453,454,455,456,459,460,461,462,463,464,465,466,467,
  468,469,470,471,484,485,486,496,497,506,507,513,514,524,545,546,547,548,549,550,
  551,552,553,555,563,564,565,566,567,570,572,573,574,575,576,577,578,
  580,581,582,583,600,601,602,614,615,624,625,630,631,641,663,664,665,666,667,668,
  670,672,680,681,682,683,684,686,687,688,689,690,691,692,693,694,695,
  73,96,98,99,772,774,775,777
};

// ---------------- Kernel 0: permuted target arrays + normals + acc init ------
__global__ __launch_bounds__(256) void k_prep(const float* __restrict__ recon,
                                              const float* __restrict__ gt,
                                              const int* __restrict__ faces,
                                              float4* __restrict__ ws4,
                                              float* __restrict__ acc) {
    int b = blockIdx.x, tid = threadIdx.x;
    if (b == 0 && tid < 16) acc[tid] = 0.0f;
    __shared__ float4 s_r[NV];
    __shared__ float s_vnx[NV], s_vny[NV], s_vnz[NV];
    __shared__ unsigned int s_bm[25];
    __shared__ unsigned short s_pre[26];
    __shared__ unsigned short s_perm[NV];

    if (tid < 25) s_bm[tid] = 0u;
    __syncthreads();
    if (tid < NPRIOR) {
        int v = c_prior[tid];
        atomicOr(&s_bm[v >> 5], 1u << (v & 31));
    }
    const float* rb = recon + (size_t)b * NV * 3;
    const float* gb = gt    + (size_t)b * NV * 3;
    float4* gt4   = ws4 + (size_t)b * BATCH_F4;
    float4* rec4p = gt4 + NVP;
    float4* nrm4p = rec4p + NVP;
    for (int j = tid; j < NV; j += 256) {
        float x = rb[3*j], y = rb[3*j+1], z = rb[3*j+2];
        s_r[j] = make_float4(x, y, z, x*x + y*y + z*z + BIAS);
        x = gb[3*j]; y = gb[3*j+1]; z = gb[3*j+2];
        gt4[j] = make_float4(x, y, z, x*x + y*y + z*z);
        s_vnx[j] = 0.0f; s_vny[j] = 0.0f; s_vnz[j] = 0.0f;
    }
    if (tid < 2) gt4[NV + tid] = make_float4(0.f, 0.f, 0.f, 1e30f);
    __syncthreads();
    if (tid == 0) {
        unsigned int run = 0;
        for (int w = 0; w < 25; ++w) { s_pre[w] = (unsigned short)run; run += __popc(s_bm[w]); }
        s_pre[25] = (unsigned short)run;
    }
    __syncthreads();
    for (int j = tid; j < NV; j += 256) {
        int w = j >> 5;
        unsigned int below = s_bm[w] & ((1u << (j & 31)) - 1u);
        int rank = s_pre[w] + __popc(below);
        bool member = (s_bm[w] >> (j & 31)) & 1u;
        int pos = member ? rank : (NPRIOR + (j - rank));
        s_perm[pos] = (unsigned short)j;
    }
    for (int f = tid; f < NFACE; f += 256) {
        int i0 = faces[3*f], i1 = faces[3*f+1], i2 = faces[3*f+2];
        float4 p0 = s_r[i0], p1 = s_r[i1], p2 = s_r[i2];
        float e1x = p1.x - p0.x, e1y = p1.y - p0.y, e1z = p1.z - p0.z;
        float e2x = p2.x - p0.x, e2y = p2.y - p0.y, e2z = p2.z - p0.z;
        float fx = e1y * e2z - e1z * e2y;
        float fy = e1z * e2x - e1x * e2z;
        float fz = e1x * e2y - e1y * e2x;
        atomicAdd(&s_vnx[i0], fx); atomicAdd(&s_vny[i0], fy); atomicAdd(&s_vnz[i0], fz);
        atomicAdd(&s_vnx[i1], fx); atomicAdd(&s_vny[i1], fy); atomicAdd(&s_vnz[i1], fz);
        atomicAdd(&s_vnx[i2], fx); atomicAdd(&s_vny[i2], fy); atomicAdd(&s_vnz[i2], fz);
    }
    __syncthreads();
    for (int j = tid; j < NVP; j += 256) {
        if (j < NV) {
            int src = s_perm[j];
            rec4p[j] = s_r[src];
            float x = s_vnx[src], y = s_vny[src], z = s_vnz[src];
            float inv = 1.0f / (sqrtf(x*x + y*y + z*z) + 1e-12f);
            nrm4p[j] = make_float4(x * inv, y * inv, z * inv, 0.0f);
        } else {
            rec4p[j] = make_float4(0.f, 0.f, 0.f, 1e30f);
            nrm4p[j] = make_float4(0.f, 0.f, 1.f, 0.0f);
        }
    }
}

#define LOAD_PTS(ob)                                                          \
    const float4* ob4 = (const float4*)((ob) + (size_t)tid * 24);             \
    float4 q0 = ob4[0], q1 = ob4[1], q2 = ob4[2],                             \
           q3 = ob4[3], q4 = ob4[4], q5 = ob4[5];                             \
    float px[PPT], py[PPT], pz[PPT];                                          \
    px[0]=q0.x; py[0]=q0.y; pz[0]=q0.z;  px[1]=q0.w; py[1]=q1.x; pz[1]=q1.y;  \
    px[2]=q1.z; py[2]=q1.w; pz[2]=q2.x;  px[3]=q2.y; py[3]=q2.z; pz[3]=q2.w;  \
    px[4]=q3.x; py[4]=q3.y; pz[4]=q3.z;  px[5]=q3.w; py[5]=q4.x; pz[5]=q4.y;  \
    px[6]=q4.z; py[6]=q4.w; pz[6]=q5.x;  px[7]=q5.y; py[7]=q5.z; pz[7]=q5.w;

// ---------------- Fused role kernel ----------------
// [0,256): rec quad-argmin + full epilogue  [256,512): gt min + gc bits
// [512,640): chamfer
__global__ __launch_bounds__(256) void k_fused(const float* __restrict__ obj,
                                               const float4* __restrict__ ws4,
                                               float* __restrict__ acc,
                                               unsigned char* __restrict__ rcA,
                                               unsigned char* __restrict__ gcA) {
    __shared__ float4 s_t[NVP];
    __shared__ float s_red[3];
    int tid = threadIdx.x;
    int blk = blockIdx.x;

    if (blk < REC_BLOCKS) {
        // ============ REC ROLE: scan + inline epilogue ============
        int b = blk >> 2, chunk = blk & 3;
        const float4* base = ws4 + (size_t)b * BATCH_F4;
        const float4* rec4p = base + NVP;
        const float4* nrm4p = base + 2 * NVP;
        for (int j = tid; j < NVP; j += 256) s_t[j] = rec4p[j];
        if (tid < 3) s_red[tid] = 0.0f;
        __syncthreads();

        const float* ob = obj + ((size_t)b * N1V + (size_t)chunk * 2048) * 3;
        LOAD_PTS(ob)
        float nax[PPT], nay[PPT], naz[PPT], m[PPT];
        int q[PPT];
#pragma unroll
        for (int i = 0; i < PPT; ++i) {
            nax[i] = -2.0f * px[i]; nay[i] = -2.0f * py[i]; naz[i] = -2.0f * pz[i];
            m[i] = 3.4e38f; q[i] = 0;
        }
        float mp[PPT];
#pragma unroll 1
        for (int jq = 0; jq < SEG1Q; ++jq) {
            int j = 4 * jq;
            float4 t0 = s_t[j], t1 = s_t[j+1], t2 = s_t[j+2], t3 = s_t[j+3];
#pragma unroll
            for (int i = 0; i < PPT; ++i) {
                float d0 = fmaf(nax[i], t0.x, fmaf(nay[i], t0.y, fmaf(naz[i], t0.z, t0.w)));
                float d1 = fmaf(nax[i], t1.x, fmaf(nay[i], t1.y, fmaf(naz[i], t1.z, t1.w)));
                float d2 = fmaf(nax[i], t2.x, fmaf(nay[i], t2.y, fmaf(naz[i], t2.z, t2.w)));
                float d3 = fmaf(nax[i], t3.x, fmaf(nay[i], t3.y, fmaf(naz[i], t3.z, t3.w)));
                float mn = fminf(fminf(fminf(d0, d1), fminf(d2, d3)), m[i]);
                q[i] = (mn < m[i]) ? jq : q[i];
                m[i] = mn;
            }
        }
#pragma unroll
        for (int i = 0; i < PPT; ++i) mp[i] = m[i];   // prior min snapshot
#pragma unroll 1
        for (int jq = SEG1Q; jq < NQ; ++jq) {
            int j = 4 * jq;
            float4 t0 = s_t[j], t1 = s_t[j+1], t2 = s_t[j+2], t3 = s_t[j+3];
#pragma unroll
            for (int i = 0; i < PPT; ++i) {
                float d0 = fmaf(nax[i], t0.x, fmaf(nay[i], t0.y, fmaf(naz[i], t0.z, t0.w)));
                float d1 = fmaf(nax[i], t1.x, fmaf(nay[i], t1.y, fmaf(naz[i], t1.z, t1.w)));
                float d2 = fmaf(nax[i], t2.x, fmaf(nay[i], t2.y, fmaf(naz[i], t2.z, t2.w)));
                float d3 = fmaf(nax[i], t3.x, fmaf(nay[i], t3.y, fmaf(naz[i], t3.z, t3.w)));
                float mn = fminf(fminf(fminf(d0, d1), fminf(d2, d3)), m[i]);
                q[i] = (mn < m[i]) ? jq : q[i];
                m[i] = mn;
            }
        }
        // ---- inline epilogue ----
        float lS_cmap = 0.0f, lN_cmap = 0.0f, lS_pen = 0.0f;
        unsigned int rcbits = 0;
#pragma unroll
        for (int i = 0; i < PPT; ++i) {
            float a2 = px[i]*px[i] + py[i]*py[i] + pz[i]*pz[i];
            float drec = fmaxf(a2 + (m[i]  - BIAS), 0.0f);
            float dpri = fmaxf(a2 + (mp[i] - BIAS), 0.0f);
            bool cm = drec < 1e-4f;
            bool rc = sqrtf(drec) < 0.005f;
            if (cm) { lS_cmap += dpri; lN_cmap += 1.0f; }
            if (rc) rcbits |= (1u << i);
            // winning-quad re-eval from LDS for jstar (bit-identical fma chain)
            int jr = 4 * q[i];
            float4 t0 = s_t[jr], t1 = s_t[jr+1], t2 = s_t[jr+2], t3 = s_t[jr+3];
            float d0 = fmaf(nax[i], t0.x, fmaf(nay[i], t0.y, fmaf(naz[i], t0.z, t0.w)));
            float d1 = fmaf(nax[i], t1.x, fmaf(nay[i], t1.y, fmaf(naz[i], t1.z, t1.w)));
            float d2 = fmaf(nax[i], t2.x, fmaf(nay[i], t2.y, fmaf(naz[i], t2.z, t2.w)));
            float d3 = fmaf(nax[i], t3.x, fmaf(nay[i], t3.y, fmaf(naz[i], t3.z, t3.w)));
            float mmin = fminf(fminf(d0, d1), fminf(d2, d3));
            int off = (d0 == mmin) ? 0 : ((d1 == mmin) ? 1 : ((d2 == mmin) ? 2 : 3));
            int jstar = jr + off;
            float4 tS = s_t[jstar];
            float4 nr = nrm4p[jstar];
            float ddot = (tS.x - px[i]) * nr.x + (tS.y - py[i]) * nr.y
                       + (tS.z - pz[i]) * nr.z;
            if (ddot > 0.0f) lS_pen += drec;
        }
        rcA[(size_t)blk * 256 + tid] = (unsigned char)rcbits;
        atomicAdd(&s_red[0], lS_cmap);
        atomicAdd(&s_red[1], lN_cmap);
        atomicAdd(&s_red[2], lS_pen);
        __syncthreads();
        if (tid == 0) atomicAdd(&acc[3], s_red[0]);
        if (tid == 1) atomicAdd(&acc[4], s_red[1]);
        if (tid == 2) atomicAdd(&acc[7], s_red[2]);
        return;
    }

    if (blk < REC_BLOCKS + GT_BLOCKS) {
        // ============ GT ROLE: min scan + gc bits ============
        int r = blk - REC_BLOCKS;
        int b = r >> 2, chunk = r & 3;
        const float4* gt4v = ws4 + (size_t)b * BATCH_F4;
        for (int j = tid; j < NVP; j += 256) s_t[j] = gt4v[j];
        if (tid == 0) s_red[0] = 0.0f;
        __syncthreads();

        const float* ob = obj + ((size_t)b * N1V + (size_t)chunk * 2048) * 3;
        LOAD_PTS(ob)
        float nax[PPT], nay[PPT], naz[PPT], mgt[PPT];
#pragma unroll
        for (int i = 0; i < PPT; ++i) {
            nax[i] = -2.0f * px[i]; nay[i] = -2.0f * py[i]; naz[i] = -2.0f * pz[i];
            mgt[i] = 3.4e38f;
        }
#pragma unroll 1
        for (int jq = 0; jq < NQ; ++jq) {
            int j = 4 * jq;
            float4 t0 = s_t[j], t1 = s_t[j+1], t2 = s_t[j+2], t3 = s_t[j+3];
#pragma unroll
            for (int i = 0; i < PPT; ++i) {
                float d0 = fmaf(nax[i], t0.x, fmaf(nay[i], t0.y, fmaf(naz[i], t0.z, t0.w)));
                float d1 = fmaf(nax[i], t1.x, fmaf(nay[i], t1.y, fmaf(naz[i], t1.z, t1.w)));
                float d2 = fmaf(nax[i], t2.x, fmaf(nay[i], t2.y, fmaf(naz[i], t2.z, t2.w)));
                float d3 = fmaf(nax[i], t3.x, fmaf(nay[i], t3.y, fmaf(naz[i], t3.z, t3.w)));
                mgt[i] = fminf(fminf(mgt[i], fminf(d0, d1)), fminf(d2, d3));
            }
        }
        float lN_gt = 0.0f;
        unsigned int gcbits = 0;
#pragma unroll
        for (int i = 0; i < PPT; ++i) {
            float a2 = px[i]*px[i] + py[i]*py[i] + pz[i]*pz[i];
            float dgt = fmaxf(a2 + mgt[i], 0.0f);
            if (sqrtf(dgt) < 0.005f) { lN_gt += 1.0f; gcbits |= (1u << i); }
        }
        gcA[(size_t)r * 256 + tid] = (unsigned char)gcbits;
        atomicAdd(&s_red[0], lN_gt);
        __syncthreads();
        if (tid == 0) atomicAdd(&acc[5], s_red[0]);
        return;
    }

    // ============ CHAMFER ROLE (4 sources/thread) ============
    {
        int c   = blk - (REC_BLOCKS + GT_BLOCKS);
        int b   = c >> 1;
        int dir = c & 1;           // 0: rec->gt, 1: gt->rec
        const float4* base = ws4 + (size_t)b * BATCH_F4;
        const float4* srcv = dir ? base : (base + NVP);   // gt4 : rec4p
        const float4* tgtv = dir ? (base + NVP) : base;   // rec4p : gt4
        for (int j = tid; j < NVP; j += 256) s_t[j] = tgtv[j];
        if (tid == 0) s_red[0] = 0.0f;
        __syncthreads();

        const int CPT = 4;
        float nax[CPT], nay[CPT], naz[CPT], a2[CPT], m[CPT];
        bool valid[CPT];
#pragma unroll
        for (int k = 0; k < CPT; ++k) {
            int p = tid + 256 * k;
            valid[k] = (p < NV);
            float4 s = srcv[valid[k] ? p : 0];
            nax[k] = -2.0f * s.x; nay[k] = -2.0f * s.y; naz[k] = -2.0f * s.z;
            a2[k] = s.w;                  // one of src/tgt carries +BIAS
            m[k] = 3.4e38f;
        }
#pragma unroll 1
        for (int j = 0; j < NVP; j += 4) {
            float4 t0 = s_t[j], t1 = s_t[j+1], t2 = s_t[j+2], t3 = s_t[j+3];
#pragma unroll
            for (int k = 0; k < CPT; ++k) {
                float d0 = fmaf(nax[k], t0.x, fmaf(nay[k], t0.y, fmaf(naz[k], t0.z, t0.w)));
                float d1 = fmaf(nax[k], t1.x, fmaf(nay[k], t1.y, fmaf(naz[k], t1.z, t1.w)));
                float d2 = fmaf(nax[k], t2.x, fmaf(nay[k], t2.y, fmaf(naz[k], t2.z, t2.w)));
                float d3 = fmaf(nax[k], t3.x, fmaf(nay[k], t3.y, fmaf(naz[k], t3.z, t3.w)));
                m[k] = fminf(fminf(m[k], fminf(d0, d1)), fminf(d2, d3));
            }
        }
        float local = 0.0f;
#pragma unroll
        for (int k = 0; k < CPT; ++k)
            if (valid[k]) local += fmaxf(a2[k] + m[k] - BIAS, 0.0f);
        atomicAdd(&s_red[0], local);
        __syncthreads();
        if (tid == 0) atomicAdd(&acc[2], s_red[0]);
    }
}

// ---------------- Combine (popcount rc&gc) + finalize (ticket) ----------------
__global__ __launch_bounds__(256) void k_combine(float* __restrict__ acc,
                                                 const unsigned int* __restrict__ rcW,
                                                 const unsigned int* __restrict__ gcW,
                                                 const float* __restrict__ mean,
                                                 const float* __restrict__ log_var,
                                                 const float* __restrict__ rp,
                                                 const float* __restrict__ xp,
                                                 float* __restrict__ out) {
    int blk = blockIdx.x, tid = threadIdx.x;
    __shared__ float s_red[2];
    __shared__ unsigned int s_ticket;
    if (tid < 2) s_red[tid] = 0.0f;
    __syncthreads();
    int idx = blk * 256 + tid;                    // 16384 uints = NPTS/8 bytes
    unsigned int rc = rcW[idx], gc = gcW[idx];
    float cnt = (float)__popc(rc & gc);
    atomicAdd(&s_red[0], cnt);
    __syncthreads();
    if (tid == 0) atomicAdd(&acc[6], s_red[0]);
    __threadfence();
    if (tid == 0) s_ticket = atomicAdd((unsigned int*)&acc[15], 1u);
    __syncthreads();

    if (s_ticket == CMB_BLOCKS - 1) {
        if (tid < 2) s_red[tid] = 0.0f;
        __syncthreads();
        float s_param = 0.0f, s_kld = 0.0f;
        for (int i = tid; i < NB * NPAR; i += 256) {
            float d = rp[i] - xp[i];
            s_param += d * d;
        }
        for (int i = tid; i < NB * NZ; i += 256) {
            float m = mean[i], lv = log_var[i];
            s_kld += 1.0f + lv - m * m - expf(lv);
        }
        atomicAdd(&s_red[0], s_param);
        atomicAdd(&s_red[1], s_kld);
        __syncthreads();
        if (tid == 0) {
            const float fB = 64.0f;
            float a2v = atomicAdd(&acc[2], 0.0f);
            float a3  = atomicAdd(&acc[3], 0.0f);
            float a4  = atomicAdd(&acc[4], 0.0f);
            float a5  = atomicAdd(&acc[5], 0.0f);
            float a6  = atomicAdd(&acc[6], 0.0f);
            float a7  = atomicAdd(&acc[7], 0.0f);
            float param_loss  = s_red[0] / fB;
            float KLD         = -0.5f * s_red[1] / fB * 10.0f;
            float recon_loss  = a2v / fB;
            float cmap_loss   = 3000.0f * a3 / (fB * a4);
            float consistency = -5.0f * a6 / (a5 + 0.0001f);
            float penetr      = 100.0f * a7 / fB;
            out[0] = (recon_loss + KLD) + 0.1f * param_loss + 1000.0f * cmap_loss
                   + 10.0f * consistency + 10.0f * penetr;
        }
    }
}

extern "C" void kernel_launch(void* const* d_in, const int* in_sizes, int n_in,
                              void* d_out, int out_size, void* d_ws, size_t ws_size,
                              hipStream_t stream) {
    (void)in_sizes; (void)n_in; (void)out_size; (void)ws_size;
    const float* obj     = (const float*)d_in[0];
    const float* recon   = (const float*)d_in[1];
    const float* gt      = (const float*)d_in[2];
    const float* mean    = (const float*)d_in[3];
    const float* log_var = (const float*)d_in[4];
    const float* rp      = (const float*)d_in[5];
    const float* xp      = (const float*)d_in[6];
    const int*   faces   = (const int*)d_in[7];
    float* acc  = (float*)d_ws + ACC_OFF;
    float4* ws4 = (float4*)d_ws;
    unsigned char* rcA = (unsigned char*)((float*)d_ws + RC_OFF);
    unsigned char* gcA = (unsigned char*)((float*)d_ws + GC_OFF);
    float* out  = (float*)d_out;

    k_prep   <<<NB,           256, 0, stream>>>(recon, gt, faces, ws4, acc);
    k_fused  <<<NROLE_BLOCKS, 256, 0, stream>>>(obj, ws4, acc, rcA, gcA);
    k_combine<<<CMB_BLOCKS,   256, 0, stream>>>(acc, (const unsigned int*)rcA,
                                                (const unsigned int*)gcA,
                                                mean, log_var, rp, xp, out);
}